// Round 7
// baseline (290.016 us; speedup 1.0000x reference)
//
#include <hip/hip_runtime.h>
#include <hip/hip_bf16.h>

#define NN 1024
#define LSTR 72  // bf16 row stride (2-way bank aliasing only — free; 16B-aligned rows)
#define EPSV 1e-5f
#define BIGINF 1e5f

typedef __attribute__((ext_vector_type(8))) short short8;
typedef __attribute__((ext_vector_type(4))) short short4v;
typedef __attribute__((ext_vector_type(4))) float f32x4;

__device__ __forceinline__ float siluf(float v) {
    return v * __builtin_amdgcn_rcpf(1.0f + __expf(-v));
}
__device__ __forceinline__ float pnorm(float dx, float dy, float dz) {
    return sqrtf(dx * dx + dy * dy + dz * dz + EPSV);
}
__device__ __forceinline__ float wsum(float v) {
#pragma unroll
    for (int off = 32; off > 0; off >>= 1) v += __shfl_xor(v, off, 64);
    return v;
}
__device__ __forceinline__ float redquad(float v) {
    v += __shfl_xor(v, 16, 64); v += __shfl_xor(v, 32, 64);
    return v;
}
__device__ __forceinline__ short f2bs(float v) {  // RNE (weights, once)
    __hip_bfloat16 b = __float2bfloat16(v);
    return *reinterpret_cast<short*>(&b);
}
__device__ __forceinline__ short f2bt(float v) {  // truncate (hot path)
    return (short)(__float_as_uint(v) >> 16);
}

// ---- kA (fused): [0,NN): HA/HB/HBT; [NN,NN+64): weight transposes; NN+64: wsv/svb ----
__global__ void kA(const float* __restrict__ h, const float* __restrict__ ew1,
                   const float* __restrict__ eb1, const float* __restrict__ ew2,
                   const float* __restrict__ cw1, const float* __restrict__ fw1,
                   const float* __restrict__ fw2, const float* __restrict__ aw,
                   const float* __restrict__ ab, const float* __restrict__ eb2,
                   float* __restrict__ HA, float* __restrict__ HB,
                   float* __restrict__ HBT, short* __restrict__ ew2T,
                   short* __restrict__ cw1T, short* __restrict__ fw1T,
                   short* __restrict__ fw2T, float* __restrict__ wsv,
                   float* __restrict__ svb) {
    const int b = blockIdx.x;
    const int o = threadIdx.x;
    if (b < NN) {
        const int i = b;
        float hv = h[i * 64 + o];
        float a = 0.f, bb = eb1[o];
#pragma unroll
        for (int k = 0; k < 64; k++) {
            float hk = __shfl(hv, k, 64);
            a += hk * ew1[k * 64 + o];
            bb += hk * ew1[(64 + k) * 64 + o];
        }
        HA[i * 64 + o] = a;
        HB[i * 64 + o] = bb;
        HBT[o * NN + i] = bb;
    } else if (b < NN + 64) {
        const int r = b - NN;
        ew2T[r * 64 + o] = f2bs(ew2[o * 64 + r]);
        cw1T[r * 64 + o] = f2bs(cw1[o * 64 + r]);
        fw1T[r * 64 + o] = f2bs(fw1[o * 64 + r]);
        if (r < 32) fw2T[r * 64 + o] = f2bs(fw2[o * 32 + r]);
    } else {
        float s = 0.f;
#pragma unroll
        for (int q = 0; q < 64; q++) s += ew2[o * 64 + q] * aw[q];
        wsv[o] = s;
        float e = wsum(eb2[o] * aw[o]);
        if (o == 0) svb[0] = e + ab[0];
    }
}

// ---- kBn: pass 1 — thread t handles j=4t..4t+3, coalesced HBT float4 loads ----
__global__ __launch_bounds__(256) void kBn(
    const float* __restrict__ x, const float* __restrict__ ew1,
    const float* __restrict__ HA, const float* __restrict__ HBT,
    const float* __restrict__ wsv, const float* __restrict__ svb,
    const float* __restrict__ lg, float* __restrict__ ls,
    float* __restrict__ rowm, float* __restrict__ rowd) {
    const int i = blockIdx.x;
    const int t = threadIdx.x;
    const float* HAi = HA + i * 64;
    const float* w1 = ew1 + 128 * 64;
    const float gamma = __expf(lg[0]);
    const float svb0 = svb[0];
    const float xi0 = x[i * 3 + 0], xi1 = x[i * 3 + 1], xi2 = x[i * 3 + 2];

    float4 xa = ((const float4*)x)[3 * t + 0];
    float4 xb = ((const float4*)x)[3 * t + 1];
    float4 xc = ((const float4*)x)[3 * t + 2];
    float nrm[4], le[4], lv[4];
    {
        float dx0 = xi0 - xa.x, dy0 = xi1 - xa.y, dz0 = xi2 - xa.z;
        float dx1 = xi0 - xa.w, dy1 = xi1 - xb.x, dz1 = xi2 - xb.y;
        float dx2 = xi0 - xb.z, dy2 = xi1 - xb.w, dz2 = xi2 - xc.x;
        float dx3 = xi0 - xc.y, dy3 = xi1 - xc.z, dz3 = xi2 - xc.w;
        nrm[0] = pnorm(dx0, dy0, dz0);
        nrm[1] = pnorm(dx1, dy1, dz1);
        nrm[2] = pnorm(dx2, dy2, dz2);
        nrm[3] = pnorm(dx3, dy3, dz3);
    }
    float d0 = 0.f, d1 = 0.f, d2 = 0.f, d3 = 0.f;
#pragma unroll 8
    for (int k = 0; k < 64; k++) {
        float4 hb = *(const float4*)&HBT[k * NN + 4 * t];
        float hk = HAi[k], w1k = w1[k], wv = wsv[k];
        d0 += siluf(hk + hb.x + nrm[0] * w1k) * wv;
        d1 += siluf(hk + hb.y + nrm[1] * w1k) * wv;
        d2 += siluf(hk + hb.z + nrm[2] * w1k) * wv;
        d3 += siluf(hk + hb.w + nrm[3] * w1k) * wv;
    }
    float me = -3.0e38f, ms = -3.0e38f;
    float4 svo;
    {
        float dd[4] = {d0, d1, d2, d3};
#pragma unroll
        for (int m = 0; m < 4; m++) {
            int j = 4 * t + m;
            float sv = dd[m] + svb0;
            sv = sv >= 0.f ? sv : 0.01f * sv;
            if (j == i) sv -= BIGINF;
            lv[m] = sv;
            le[m] = -(nrm[m] + (j == i ? BIGINF : 0.f)) * gamma;
            me = fmaxf(me, le[m]);
            ms = fmaxf(ms, lv[m]);
        }
        svo.x = lv[0]; svo.y = lv[1]; svo.z = lv[2]; svo.w = lv[3];
    }
    *(float4*)&ls[(size_t)i * NN + 4 * t] = svo;

    __shared__ float sm[4], ss[4], s1[4], s2[4], s3[4];
#pragma unroll
    for (int off = 32; off > 0; off >>= 1) {
        me = fmaxf(me, __shfl_xor(me, off, 64));
        ms = fmaxf(ms, __shfl_xor(ms, off, 64));
    }
    const int w = t >> 6;
    if ((t & 63) == 0) { sm[w] = me; ss[w] = ms; }
    __syncthreads();
    me = fmaxf(fmaxf(sm[0], sm[1]), fmaxf(sm[2], sm[3]));
    ms = fmaxf(fmaxf(ss[0], ss[1]), fmaxf(ss[2], ss[3]));
    float Se = 0.f, Ss = 0.f, Sq = 0.f;
#pragma unroll
    for (int m = 0; m < 4; m++) {
        float ee = __expf(le[m] - me);
        float es = __expf(lv[m] - ms);
        Se += ee; Ss += es; Sq += ee * es;
    }
    Se = wsum(Se); Ss = wsum(Ss); Sq = wsum(Sq);
    if ((t & 63) == 0) { s1[w] = Se; s2[w] = Ss; s3[w] = Sq; }
    __syncthreads();
    if (t == 0) {
        rowm[i] = me + ms;
        rowd[i] = (s3[0] + s3[1] + s3[2] + s3[3]) +
                  EPSV * (s1[0] + s1[1] + s1[2] + s1[3]) * (s2[0] + s2[1] + s2[2] + s2[3]);
    }
}

// stage bf16 weight rows into LDS stride-LSTR
__device__ __forceinline__ void stageW(const short* __restrict__ g, short* s,
                                       int tid, int rows, int step) {
    for (int c = tid; c < rows * 16; c += step) {
        int r = c >> 4, q = c & 15;
        *(short4v*)&s[r * LSTR + q * 4] = *(const short4v*)&g[r * 64 + q * 4];
    }
}

// ---- kD: one i per block, 16 j-subtiles of 64, ONE 16-row tile per wave ----
// j-contractions (hagg / xupd-H2 / combos-G / sd) live in 31 persistent regs,
// reduced ONCE at block end:
//   combos = fw2^T @ G + fb2 * sd^T,  G[m,d]  = sum_j wv[j,m]*dirs[j,d]
//   xupd   = cw2 . H2,               H2[n,d] = sum_j s[j,n]*dx[j,d]
// r5 landed zero-spill at VGPR=128 (FETCH 4.5MB/WRITE 3.9MB legit), kD 144us,
// but VALUBusy 48% / occupancy 22.6% — latency-bound, no pipe saturated.
// This round (latency levers, work constant):
//  - cw1T staged to LDS (sWc): per-jt GEMM2 B-frags were 8 global_load_dwordx4
//    at ~200cy L2 latency per wave per jt; now ~20cy ds_reads.
//  - 256-thread blocks (4 waves, 16 jt): ~39KB LDS -> 4 blocks/CU co-resident
//    (vs 2) at the same VGPR=128 / 4 waves-per-SIMD point; same per-wave body.
// (r6 run was an infra failure — container died twice, no compile/pytest
// signal; resubmitted unchanged.)
__global__ __launch_bounds__(256) void kD(
    const float* __restrict__ x, const float* __restrict__ ew1,
    const float* __restrict__ eb2, const float* __restrict__ cb1,
    const float* __restrict__ fb1, const float* __restrict__ lg,
    const float* __restrict__ HA, const float* __restrict__ HB,
    const short* __restrict__ ew2T, const short* __restrict__ cw1T,
    const short* __restrict__ fw1T,
    const float* __restrict__ ls, const float* __restrict__ rowm,
    const float* __restrict__ rowd, float* __restrict__ hagg,
    float* __restrict__ Gw, float* __restrict__ H2w, float* __restrict__ sdw) {
    __shared__ __align__(16) short sWe[64 * LSTR];   // ew2
    __shared__ __align__(16) short sWf[64 * LSTR];   // fw1
    __shared__ __align__(16) short sWc[64 * LSTR];   // cw1 (was global per-jt)
    __shared__ __align__(16) short sScr[4][16 * LSTR];  // 1 per wave (he only)
    __shared__ float sHag[64], sG[192], sH2[192], sSd[3];

    const int tid = threadIdx.x;
    const int i = blockIdx.x;
    const int lane = tid & 63, w = tid >> 6;       // wave 0..3
    const int col = lane & 15, quad = lane >> 4;

    stageW(ew2T, sWe, tid, 64, 256);
    stageW(fw1T, sWf, tid, 64, 256);
    stageW(cw1T, sWc, tid, 64, 256);
    for (int c = tid; c < 451; c += 256) {
        if (c < 64) sHag[c] = 0.f;
        else if (c < 256) sG[c - 64] = 0.f;
        else if (c < 448) sH2[c - 256] = 0.f;
        else sSd[c - 448] = 0.f;
    }

    short* scr = sScr[w];
    const float gamma = __expf(lg[0]);

    float eb[4], cbv[4], fbv[4];
#pragma unroll
    for (int nb = 0; nb < 4; nb++) {
        eb[nb] = eb2[nb * 16 + col];
        cbv[nb] = cb1[nb * 16 + col];
        fbv[nb] = fb1[nb * 16 + col];
    }
    const float rm = rowm[i];
    const float invd = 1.0f / rowd[i];
    const float xi0 = x[i * 3 + 0], xi1 = x[i * 3 + 1], xi2 = x[i * 3 + 2];
    const float* lsi = ls + (size_t)i * NN;

    float hagA[4] = {0.f, 0.f, 0.f, 0.f};
    float Ga[12]  = {0.f, 0.f, 0.f, 0.f, 0.f, 0.f, 0.f, 0.f, 0.f, 0.f, 0.f, 0.f};
    float H2a[12] = {0.f, 0.f, 0.f, 0.f, 0.f, 0.f, 0.f, 0.f, 0.f, 0.f, 0.f, 0.f};
    float sdx = 0.f, sdy = 0.f, sdz = 0.f;
    __syncthreads();  // weights staged + accumulators zeroed

#pragma unroll 1
    for (int jt = 0; jt < 16; jt++) {
        const int r = jt * 64 + w * 16 + col;
        // geometry (same row for all 4 quads -> sd dup x4, rescaled at end)
        float dx = xi0 - x[r * 3 + 0], dy = xi1 - x[r * 3 + 1], dz = xi2 - x[r * 3 + 2];
        float nr = pnorm(dx, dy, dz);
        float iv = __builtin_amdgcn_rcpf(nr + 1.0f);
        sdx += dx * iv; sdy += dy * iv; sdz += dz * iv;
        float le = -(nr + (r == i ? BIGINF : 0.f)) * gamma;
        float cb = __expf(le + lsi[r] - rm) * invd;

        // A-frag (HA/ew1 reloaded per jt: L2-hot, keeps pressure down)
        short8 af[2];
#pragma unroll
        for (int kb = 0; kb < 2; kb++) {
            const float* hA = &HA[i * 64 + kb * 32 + quad * 8];
            const float* wr = &ew1[128 * 64 + kb * 32 + quad * 8];
            const float* hb = &HB[r * 64 + kb * 32 + quad * 8];
#pragma unroll
            for (int t = 0; t < 8; t++)
                af[kb][t] = f2bt(siluf(hA[t] + hb[t] + nr * wr[t]));
        }
        // GEMM1: he = U@ew2 + eb2
        f32x4 ac[4] = {{0.f,0.f,0.f,0.f},{0.f,0.f,0.f,0.f},{0.f,0.f,0.f,0.f},{0.f,0.f,0.f,0.f}};
#pragma unroll
        for (int kb = 0; kb < 2; kb++) {
#pragma unroll
            for (int nb = 0; nb < 4; nb++) {
                short8 b = *(const short8*)&sWe[(nb * 16 + col) * LSTR + kb * 32 + quad * 8];
                ac[nb] = __builtin_amdgcn_mfma_f32_16x16x32_bf16(af[kb], b, ac[nb], 0, 0, 0);
            }
        }
        // comb broadcast (C-layout row = quad*4+reg)
        float cm[4];
#pragma unroll
        for (int reg = 0; reg < 4; reg++) cm[reg] = __shfl(cb, quad * 4 + reg, 64);
        // he epilogue: scratch + hagg register accumulation
#pragma unroll
        for (int nb = 0; nb < 4; nb++) {
#pragma unroll
            for (int reg = 0; reg < 4; reg++) {
                float h0 = ac[nb][reg] + eb[nb];
                scr[(quad * 4 + reg) * LSTR + nb * 16 + col] = f2bt(h0);
                hagA[nb] += h0 * cm[reg];
            }
        }
        short8 a0 = *(const short8*)&scr[col * LSTR + quad * 8];
        short8 a1 = *(const short8*)&scr[col * LSTR + 32 + quad * 8];

        // GEMM2 (phi-pre) — cw1 B-frags from LDS — H2 accumulation
        {
            f32x4 p[4] = {{0.f,0.f,0.f,0.f},{0.f,0.f,0.f,0.f},{0.f,0.f,0.f,0.f},{0.f,0.f,0.f,0.f}};
#pragma unroll
            for (int nb = 0; nb < 4; nb++) {
                short8 b0 = *(const short8*)&sWc[(nb * 16 + col) * LSTR + quad * 8];
                short8 b1 = *(const short8*)&sWc[(nb * 16 + col) * LSTR + 32 + quad * 8];
                p[nb] = __builtin_amdgcn_mfma_f32_16x16x32_bf16(a0, b0, p[nb], 0, 0, 0);
                p[nb] = __builtin_amdgcn_mfma_f32_16x16x32_bf16(a1, b1, p[nb], 0, 0, 0);
            }
#pragma unroll
            for (int reg = 0; reg < 4; reg++) {
                int sl = quad * 4 + reg;
                float tx = __shfl(dx, sl, 64), ty = __shfl(dy, sl, 64), tz = __shfl(dz, sl, 64);
#pragma unroll
                for (int nb = 0; nb < 4; nb++) {
                    float s0 = siluf(p[nb][reg] + cbv[nb]);
                    H2a[nb * 3 + 0] += s0 * tx;
                    H2a[nb * 3 + 1] += s0 * ty;
                    H2a[nb * 3 + 2] += s0 * tz;
                }
            }
        }

        // GEMM-V: v = he@fw1; wv = silu(comb*v + fb1) consumed in-register -> G
        {
            f32x4 v[4] = {{0.f,0.f,0.f,0.f},{0.f,0.f,0.f,0.f},{0.f,0.f,0.f,0.f},{0.f,0.f,0.f,0.f}};
#pragma unroll
            for (int nb = 0; nb < 4; nb++) {
                short8 b0 = *(const short8*)&sWf[(nb * 16 + col) * LSTR + quad * 8];
                short8 b1 = *(const short8*)&sWf[(nb * 16 + col) * LSTR + 32 + quad * 8];
                v[nb] = __builtin_amdgcn_mfma_f32_16x16x32_bf16(a0, b0, v[nb], 0, 0, 0);
                v[nb] = __builtin_amdgcn_mfma_f32_16x16x32_bf16(a1, b1, v[nb], 0, 0, 0);
            }
#pragma unroll
            for (int reg = 0; reg < 4; reg++) {
                int sl = quad * 4 + reg;
                float ti = __shfl(iv, sl, 64);
                float fx = __shfl(dx, sl, 64) * ti;
                float fy = __shfl(dy, sl, 64) * ti;
                float fz = __shfl(dz, sl, 64) * ti;
#pragma unroll
                for (int nb = 0; nb < 4; nb++) {
                    float w0 = siluf(cm[reg] * v[nb][reg] + fbv[nb]);
                    Ga[nb * 3 + 0] += w0 * fx;
                    Ga[nb * 3 + 1] += w0 * fy;
                    Ga[nb * 3 + 2] += w0 * fz;
                }
            }
        }
    }  // jt

    // ---- one-shot reductions (once per block) ----
#pragma unroll
    for (int nb = 0; nb < 4; nb++) {
        float v = redquad(hagA[nb]);
        if (quad == 0) atomicAdd(&sHag[nb * 16 + col], v);
    }
#pragma unroll
    for (int nb = 0; nb < 4; nb++) {
#pragma unroll
        for (int d = 0; d < 3; d++) {
            float v = redquad(H2a[nb * 3 + d]);
            if (quad == 0) atomicAdd(&sH2[(nb * 16 + col) * 3 + d], v);
            float g = redquad(Ga[nb * 3 + d]);
            if (quad == 0) atomicAdd(&sG[(nb * 16 + col) * 3 + d], g);
        }
    }
    sdx = wsum(sdx); sdy = wsum(sdy); sdz = wsum(sdz);
    if (lane == 0) {  // quads quadruplicate the rows -> exact 0.25 rescale
        atomicAdd(&sSd[0], 0.25f * sdx);
        atomicAdd(&sSd[1], 0.25f * sdy);
        atomicAdd(&sSd[2], 0.25f * sdz);
    }
    __syncthreads();  // all waves' LDS atomics done
    for (int c = tid; c < 451; c += 256) {
        if (c < 64) hagg[i * 64 + c] = sHag[c];
        else if (c < 256) Gw[i * 192 + c - 64] = sG[c - 64];
        else if (c < 448) H2w[i * 192 + c - 256] = sH2[c - 256];
        else sdw[i * 3 + c - 448] = sSd[c - 448];
    }
}

// ---- kE: combos/xupd finish (f32) + post MLPs + node update + coord output ----
__global__ void kE(const float* __restrict__ h, const float* __restrict__ x,
                   const float* __restrict__ nw1, const float* __restrict__ nb1,
                   const float* __restrict__ nw2, const float* __restrict__ nb2,
                   const float* __restrict__ pw1, const float* __restrict__ pb1,
                   const float* __restrict__ pw2, const float* __restrict__ pb2,
                   const float* __restrict__ fw2, const float* __restrict__ fb2,
                   const float* __restrict__ cw2,
                   const float* __restrict__ hagg, const float* __restrict__ Gw,
                   const float* __restrict__ H2w, const float* __restrict__ sdw,
                   float* __restrict__ out) {
    const int i = blockIdx.x, o = threadIdx.x;
    const float invN = 1.0f / (float)NN;
    // xupd[d] = sum_n cw2[n] * H2[n][d]
    float cw2o = cw2[o];
    float xd0 = wsum(cw2o * H2w[i * 192 + o * 3 + 0]);
    float xd1 = wsum(cw2o * H2w[i * 192 + o * 3 + 1]);
    float xd2 = wsum(cw2o * H2w[i * 192 + o * 3 + 2]);
    // combos[c][d] = sum_m fw2[m][c]*G[m][d] + fb2[c]*sd[d]
    float g0 = Gw[i * 192 + o * 3 + 0];
    float g1 = Gw[i * 192 + o * 3 + 1];
    float g2 = Gw[i * 192 + o * 3 + 2];
    float v0 = 0.f, v1 = 0.f, v2 = 0.f;
#pragma unroll
    for (int m = 0; m < 64; m++) {
        float fw = fw2[m * 32 + (o & 31)];
        v0 += __shfl(g0, m, 64) * fw;
        v1 += __shfl(g1, m, 64) * fw;
        v2 += __shfl(g2, m, 64) * fw;
    }
    float r = 0.f;
    if (o < 32) {
        float fb = fb2[o];
        float u0 = (v0 + fb * sdw[i * 3 + 0]) * invN;
        float u1 = (v1 + fb * sdw[i * 3 + 1]) * invN;
        float u2 = (v2 + fb * sdw[i * 3 + 2]) * invN;
        r = u0 * u0 + u1 * u1 + u2 * u2;
    }
    float t1 = pb1[o];
#pragma unroll
    for (int k = 0; k < 32; k++) t1 += __shfl(r, k, 64) * pw1[k * 64 + o];
    t1 = siluf(t1);
    float hc = pb2[o];
#pragma unroll
    for (int k = 0; k < 64; k++) hc += __shfl(t1, k, 64) * pw2[k * 64 + o];
    float hi = h[i * 64 + o];
    float ha = hagg[i * 64 + o];
    float t2 = nb1[o];
#pragma unroll
    for (int k = 0; k < 64; k++) t2 += __shfl(hi, k, 64) * nw1[k * 64 + o];
#pragma unroll
    for (int k = 0; k < 64; k++) t2 += __shfl(ha, k, 64) * nw1[(64 + k) * 64 + o];
#pragma unroll
    for (int k = 0; k < 64; k++) t2 += __shfl(hc, k, 64) * nw1[(128 + k) * 64 + o];
    t2 = siluf(t2);
    float ho = hi + nb2[o];
#pragma unroll
    for (int k = 0; k < 64; k++) ho += __shfl(t2, k, 64) * nw2[k * 64 + o];
    out[i * 64 + o] = ho;
    if (o < 3) {
        float xdv = o == 0 ? xd0 : (o == 1 ? xd1 : xd2);
        out[NN * 64 + i * 3 + o] = x[i * 3 + o] + xdv * invN;
    }
}

extern "C" void kernel_launch(void* const* d_in, const int* in_sizes, int n_in,
                              void* d_out, int out_size, void* d_ws, size_t ws_size,
                              hipStream_t stream) {
    (void)in_sizes; (void)n_in; (void)out_size; (void)ws_size;
    const float* h   = (const float*)d_in[0];
    const float* x   = (const float*)d_in[1];
    const float* ew1 = (const float*)d_in[2];
    const float* eb1 = (const float*)d_in[3];
    const float* ew2 = (const float*)d_in[4];
    const float* eb2 = (const float*)d_in[5];
    const float* nw1 = (const float*)d_in[6];
    const float* nb1 = (const float*)d_in[7];
    const float* nw2 = (const float*)d_in[8];
    const float* nb2 = (const float*)d_in[9];
    const float* cw1 = (const float*)d_in[10];
    const float* cb1 = (const float*)d_in[11];
    const float* cw2 = (const float*)d_in[12];
    const float* aw  = (const float*)d_in[13];
    const float* ab  = (const float*)d_in[14];
    const float* fw1 = (const float*)d_in[15];
    const float* fb1 = (const float*)d_in[16];
    const float* fw2 = (const float*)d_in[17];
    const float* fb2 = (const float*)d_in[18];
    const float* pw1 = (const float*)d_in[19];
    const float* pb1 = (const float*)d_in[20];
    const float* pw2 = (const float*)d_in[21];
    const float* pb2 = (const float*)d_in[22];
    const float* lg  = (const float*)d_in[23];
    float* out = (float*)d_out;

    float* W      = (float*)d_ws;
    float* ls     = W;                        // N*N
    float* HA     = ls + (size_t)NN * NN;     // N*64
    float* HB     = HA + NN * 64;             // N*64
    float* HBT    = HB + NN * 64;             // 64*N
    float* rowm   = HBT + NN * 64;            // N
    float* rowd   = rowm + NN;                // N
    float* hagg   = rowd + NN;                // N*64   (direct store)
    float* combos = hagg + NN * 64;           // N*96   (legacy slot, unused)
    float* xupd   = combos + NN * 96;         // N*3    (legacy slot, unused)
    float* wsv    = xupd + NN * 3;            // 64
    float* svb    = wsv + 64;                 // 1
    short* ew2T   = (short*)(svb + 4);        // 64*64 bf16
    short* cw1T   = ew2T + 64 * 64;
    short* fw1T   = cw1T + 64 * 64;
    short* fw2T   = fw1T + 64 * 64;           // 32*64 bf16 (legacy, unused)
    float* Gw     = (float*)(fw2T + 32 * 64); // N*192
    float* H2w    = Gw + (size_t)NN * 192;    // N*192
    float* sdw    = H2w + (size_t)NN * 192;   // N*3

    kA<<<NN + 65, 64, 0, stream>>>(h, ew1, eb1, ew2, cw1, fw1, fw2, aw, ab, eb2,
                                   HA, HB, HBT, ew2T, cw1T, fw1T, fw2T, wsv, svb);
    kBn<<<NN, 256, 0, stream>>>(x, ew1, HA, HBT, wsv, svb, lg, ls, rowm, rowd);
    kD<<<NN, 256, 0, stream>>>(x, ew1, eb2, cb1, fb1, lg, HA, HB,
                               ew2T, cw1T, fw1T, ls, rowm, rowd,
                               hagg, Gw, H2w, sdw);
    kE<<<NN, 64, 0, stream>>>(h, x, nw1, nb1, nw2, nb2, pw1, pb1, pw2, pb2,
                              fw2, fb2, cw2, hagg, Gw, H2w, sdw, out);
}

// Round 8
// 257.521 us; speedup vs baseline: 1.1262x; 1.1262x over previous
//
#include <hip/hip_runtime.h>
#include <hip/hip_bf16.h>

#define NN 1024
#define LSTR 72  // bf16 row stride (2-way bank aliasing only — free; 16B-aligned rows)
#define EPSV 1e-5f
#define BIGINF 1e5f

typedef __attribute__((ext_vector_type(8))) short short8;
typedef __attribute__((ext_vector_type(4))) short short4v;
typedef __attribute__((ext_vector_type(4))) float f32x4;

__device__ __forceinline__ float siluf(float v) {
    return v * __builtin_amdgcn_rcpf(1.0f + __expf(-v));
}
__device__ __forceinline__ float pnorm(float dx, float dy, float dz) {
    return sqrtf(dx * dx + dy * dy + dz * dz + EPSV);
}
__device__ __forceinline__ float wsum(float v) {
#pragma unroll
    for (int off = 32; off > 0; off >>= 1) v += __shfl_xor(v, off, 64);
    return v;
}
__device__ __forceinline__ float redquad(float v) {
    v += __shfl_xor(v, 16, 64); v += __shfl_xor(v, 32, 64);
    return v;
}
__device__ __forceinline__ short f2bs(float v) {  // RNE (weights, once)
    __hip_bfloat16 b = __float2bfloat16(v);
    return *reinterpret_cast<short*>(&b);
}
__device__ __forceinline__ short f2bt(float v) {  // truncate (hot path)
    return (short)(__float_as_uint(v) >> 16);
}

// ---- kA (fused): [0,NN): HA/HB/HBT; [NN,NN+64): weight transposes; NN+64: wsv/svb ----
__global__ void kA(const float* __restrict__ h, const float* __restrict__ ew1,
                   const float* __restrict__ eb1, const float* __restrict__ ew2,
                   const float* __restrict__ cw1, const float* __restrict__ fw1,
                   const float* __restrict__ fw2, const float* __restrict__ aw,
                   const float* __restrict__ ab, const float* __restrict__ eb2,
                   float* __restrict__ HA, float* __restrict__ HB,
                   float* __restrict__ HBT, short* __restrict__ ew2T,
                   short* __restrict__ cw1T, short* __restrict__ fw1T,
                   short* __restrict__ fw2T, float* __restrict__ wsv,
                   float* __restrict__ svb) {
    const int b = blockIdx.x;
    const int o = threadIdx.x;
    if (b < NN) {
        const int i = b;
        float hv = h[i * 64 + o];
        float a = 0.f, bb = eb1[o];
#pragma unroll
        for (int k = 0; k < 64; k++) {
            float hk = __shfl(hv, k, 64);
            a += hk * ew1[k * 64 + o];
            bb += hk * ew1[(64 + k) * 64 + o];
        }
        HA[i * 64 + o] = a;
        HB[i * 64 + o] = bb;
        HBT[o * NN + i] = bb;
    } else if (b < NN + 64) {
        const int r = b - NN;
        ew2T[r * 64 + o] = f2bs(ew2[o * 64 + r]);
        cw1T[r * 64 + o] = f2bs(cw1[o * 64 + r]);
        fw1T[r * 64 + o] = f2bs(fw1[o * 64 + r]);
        if (r < 32) fw2T[r * 64 + o] = f2bs(fw2[o * 32 + r]);
    } else {
        float s = 0.f;
#pragma unroll
        for (int q = 0; q < 64; q++) s += ew2[o * 64 + q] * aw[q];
        wsv[o] = s;
        float e = wsum(eb2[o] * aw[o]);
        if (o == 0) svb[0] = e + ab[0];
    }
}

// ---- kBn: pass 1 — thread t handles j=4t..4t+3, coalesced HBT float4 loads ----
__global__ __launch_bounds__(256) void kBn(
    const float* __restrict__ x, const float* __restrict__ ew1,
    const float* __restrict__ HA, const float* __restrict__ HBT,
    const float* __restrict__ wsv, const float* __restrict__ svb,
    const float* __restrict__ lg, float* __restrict__ ls,
    float* __restrict__ rowm, float* __restrict__ rowd) {
    const int i = blockIdx.x;
    const int t = threadIdx.x;
    const float* HAi = HA + i * 64;
    const float* w1 = ew1 + 128 * 64;
    const float gamma = __expf(lg[0]);
    const float svb0 = svb[0];
    const float xi0 = x[i * 3 + 0], xi1 = x[i * 3 + 1], xi2 = x[i * 3 + 2];

    float4 xa = ((const float4*)x)[3 * t + 0];
    float4 xb = ((const float4*)x)[3 * t + 1];
    float4 xc = ((const float4*)x)[3 * t + 2];
    float nrm[4], le[4], lv[4];
    {
        float dx0 = xi0 - xa.x, dy0 = xi1 - xa.y, dz0 = xi2 - xa.z;
        float dx1 = xi0 - xa.w, dy1 = xi1 - xb.x, dz1 = xi2 - xb.y;
        float dx2 = xi0 - xb.z, dy2 = xi1 - xb.w, dz2 = xi2 - xc.x;
        float dx3 = xi0 - xc.y, dy3 = xi1 - xc.z, dz3 = xi2 - xc.w;
        nrm[0] = pnorm(dx0, dy0, dz0);
        nrm[1] = pnorm(dx1, dy1, dz1);
        nrm[2] = pnorm(dx2, dy2, dz2);
        nrm[3] = pnorm(dx3, dy3, dz3);
    }
    float d0 = 0.f, d1 = 0.f, d2 = 0.f, d3 = 0.f;
#pragma unroll 8
    for (int k = 0; k < 64; k++) {
        float4 hb = *(const float4*)&HBT[k * NN + 4 * t];
        float hk = HAi[k], w1k = w1[k], wv = wsv[k];
        d0 += siluf(hk + hb.x + nrm[0] * w1k) * wv;
        d1 += siluf(hk + hb.y + nrm[1] * w1k) * wv;
        d2 += siluf(hk + hb.z + nrm[2] * w1k) * wv;
        d3 += siluf(hk + hb.w + nrm[3] * w1k) * wv;
    }
    float me = -3.0e38f, ms = -3.0e38f;
    float4 svo;
    {
        float dd[4] = {d0, d1, d2, d3};
#pragma unroll
        for (int m = 0; m < 4; m++) {
            int j = 4 * t + m;
            float sv = dd[m] + svb0;
            sv = sv >= 0.f ? sv : 0.01f * sv;
            if (j == i) sv -= BIGINF;
            lv[m] = sv;
            le[m] = -(nrm[m] + (j == i ? BIGINF : 0.f)) * gamma;
            me = fmaxf(me, le[m]);
            ms = fmaxf(ms, lv[m]);
        }
        svo.x = lv[0]; svo.y = lv[1]; svo.z = lv[2]; svo.w = lv[3];
    }
    *(float4*)&ls[(size_t)i * NN + 4 * t] = svo;

    __shared__ float sm[4], ss[4], s1[4], s2[4], s3[4];
#pragma unroll
    for (int off = 32; off > 0; off >>= 1) {
        me = fmaxf(me, __shfl_xor(me, off, 64));
        ms = fmaxf(ms, __shfl_xor(ms, off, 64));
    }
    const int w = t >> 6;
    if ((t & 63) == 0) { sm[w] = me; ss[w] = ms; }
    __syncthreads();
    me = fmaxf(fmaxf(sm[0], sm[1]), fmaxf(sm[2], sm[3]));
    ms = fmaxf(fmaxf(ss[0], ss[1]), fmaxf(ss[2], ss[3]));
    float Se = 0.f, Ss = 0.f, Sq = 0.f;
#pragma unroll
    for (int m = 0; m < 4; m++) {
        float ee = __expf(le[m] - me);
        float es = __expf(lv[m] - ms);
        Se += ee; Ss += es; Sq += ee * es;
    }
    Se = wsum(Se); Ss = wsum(Ss); Sq = wsum(Sq);
    if ((t & 63) == 0) { s1[w] = Se; s2[w] = Ss; s3[w] = Sq; }
    __syncthreads();
    if (t == 0) {
        rowm[i] = me + ms;
        rowd[i] = (s3[0] + s3[1] + s3[2] + s3[3]) +
                  EPSV * (s1[0] + s1[1] + s1[2] + s1[3]) * (s2[0] + s2[1] + s2[2] + s2[3]);
    }
}

// stage bf16 weight rows into LDS stride-LSTR (512-thread version)
__device__ __forceinline__ void stageW(const short* __restrict__ g, short* s,
                                       int tid, int rows) {
    for (int c = tid; c < rows * 16; c += 512) {
        int r = c >> 4, q = c & 15;
        *(short4v*)&s[r * LSTR + q * 4] = *(const short4v*)&g[r * 64 + q * 4];
    }
}

// ---- kD: one i per block, 8 j-subtiles of 128, ONE 16-row tile per wave ----
// (r5 config: 512 threads, VGPR=128 zero-spill, best measured 144us. r7's
// 256-thread variant: VGPR 148, occupancy 11%, same dur -> kD time is
// occupancy-INVARIANT (VALU+dep-chain bound). Reverted.)
// This round: tiny finishes move from kE into the block-end, reading sG/sH2
// directly from LDS (saves kE's 3x64-shuffle serial chains + Gw/H2w traffic):
//   combos[c,d] = sum_m fw2[m,c]*G[m,d] + fb2[c]*sd[d]   (96 dots of K=64)
//   xupd[d]    = sum_n cw2[n]*H2[n,d]                    (3 dots of K=64)
// cw1T stays LDS-staged (sWc, r7's one principled change).
__global__ __launch_bounds__(512) void kD(
    const float* __restrict__ x, const float* __restrict__ ew1,
    const float* __restrict__ eb2, const float* __restrict__ cb1,
    const float* __restrict__ fb1, const float* __restrict__ lg,
    const float* __restrict__ fw2, const float* __restrict__ fb2,
    const float* __restrict__ cw2,
    const float* __restrict__ HA, const float* __restrict__ HB,
    const short* __restrict__ ew2T, const short* __restrict__ cw1T,
    const short* __restrict__ fw1T,
    const float* __restrict__ ls, const float* __restrict__ rowm,
    const float* __restrict__ rowd, float* __restrict__ hagg,
    float* __restrict__ combos, float* __restrict__ xupd) {
    __shared__ __align__(16) short sWe[64 * LSTR];   // ew2
    __shared__ __align__(16) short sWf[64 * LSTR];   // fw1
    __shared__ __align__(16) short sWc[64 * LSTR];   // cw1
    __shared__ __align__(16) short sScr[8][16 * LSTR];  // 1 per wave (he only)
    __shared__ float sHag[64], sG[192], sH2[192], sSd[3];

    const int tid = threadIdx.x;
    const int i = blockIdx.x;
    const int lane = tid & 63, w = tid >> 6;       // wave 0..7
    const int col = lane & 15, quad = lane >> 4;

    stageW(ew2T, sWe, tid, 64);
    stageW(fw1T, sWf, tid, 64);
    stageW(cw1T, sWc, tid, 64);
    if (tid < 64) sHag[tid] = 0.f;
    else if (tid < 256) sG[tid - 64] = 0.f;
    else if (tid < 448) sH2[tid - 256] = 0.f;
    else if (tid < 451) sSd[tid - 448] = 0.f;

    short* scr = sScr[w];
    const float gamma = __expf(lg[0]);

    float eb[4], cbv[4], fbv[4];
#pragma unroll
    for (int nb = 0; nb < 4; nb++) {
        eb[nb] = eb2[nb * 16 + col];
        cbv[nb] = cb1[nb * 16 + col];
        fbv[nb] = fb1[nb * 16 + col];
    }
    const float rm = rowm[i];
    const float invd = 1.0f / rowd[i];
    const float xi0 = x[i * 3 + 0], xi1 = x[i * 3 + 1], xi2 = x[i * 3 + 2];
    const float* lsi = ls + (size_t)i * NN;

    float hagA[4] = {0.f, 0.f, 0.f, 0.f};
    float Ga[12]  = {0.f, 0.f, 0.f, 0.f, 0.f, 0.f, 0.f, 0.f, 0.f, 0.f, 0.f, 0.f};
    float H2a[12] = {0.f, 0.f, 0.f, 0.f, 0.f, 0.f, 0.f, 0.f, 0.f, 0.f, 0.f, 0.f};
    float sdx = 0.f, sdy = 0.f, sdz = 0.f;
    __syncthreads();  // weights staged + accumulators zeroed

#pragma unroll 1
    for (int jt = 0; jt < 8; jt++) {
        const int r = jt * 128 + w * 16 + col;
        // geometry (same row for all 4 quads -> sd dup x4, rescaled at end)
        float dx = xi0 - x[r * 3 + 0], dy = xi1 - x[r * 3 + 1], dz = xi2 - x[r * 3 + 2];
        float nr = pnorm(dx, dy, dz);
        float iv = __builtin_amdgcn_rcpf(nr + 1.0f);
        sdx += dx * iv; sdy += dy * iv; sdz += dz * iv;
        float le = -(nr + (r == i ? BIGINF : 0.f)) * gamma;
        float cb = __expf(le + lsi[r] - rm) * invd;

        // A-frag (HA/ew1 reloaded per jt: L2-hot, keeps pressure down)
        short8 af[2];
#pragma unroll
        for (int kb = 0; kb < 2; kb++) {
            const float* hA = &HA[i * 64 + kb * 32 + quad * 8];
            const float* wr = &ew1[128 * 64 + kb * 32 + quad * 8];
            const float* hb = &HB[r * 64 + kb * 32 + quad * 8];
#pragma unroll
            for (int t = 0; t < 8; t++)
                af[kb][t] = f2bt(siluf(hA[t] + hb[t] + nr * wr[t]));
        }
        // GEMM1: he = U@ew2 + eb2
        f32x4 ac[4] = {{0.f,0.f,0.f,0.f},{0.f,0.f,0.f,0.f},{0.f,0.f,0.f,0.f},{0.f,0.f,0.f,0.f}};
#pragma unroll
        for (int kb = 0; kb < 2; kb++) {
#pragma unroll
            for (int nb = 0; nb < 4; nb++) {
                short8 b = *(const short8*)&sWe[(nb * 16 + col) * LSTR + kb * 32 + quad * 8];
                ac[nb] = __builtin_amdgcn_mfma_f32_16x16x32_bf16(af[kb], b, ac[nb], 0, 0, 0);
            }
        }
        // comb broadcast (C-layout row = quad*4+reg)
        float cm[4];
#pragma unroll
        for (int reg = 0; reg < 4; reg++) cm[reg] = __shfl(cb, quad * 4 + reg, 64);
        // he epilogue: scratch + hagg register accumulation
#pragma unroll
        for (int nb = 0; nb < 4; nb++) {
#pragma unroll
            for (int reg = 0; reg < 4; reg++) {
                float h0 = ac[nb][reg] + eb[nb];
                scr[(quad * 4 + reg) * LSTR + nb * 16 + col] = f2bt(h0);
                hagA[nb] += h0 * cm[reg];
            }
        }
        short8 a0 = *(const short8*)&scr[col * LSTR + quad * 8];
        short8 a1 = *(const short8*)&scr[col * LSTR + 32 + quad * 8];

        // GEMM2 (phi-pre) — cw1 B-frags from LDS — H2 accumulation
        {
            f32x4 p[4] = {{0.f,0.f,0.f,0.f},{0.f,0.f,0.f,0.f},{0.f,0.f,0.f,0.f},{0.f,0.f,0.f,0.f}};
#pragma unroll
            for (int nb = 0; nb < 4; nb++) {
                short8 b0 = *(const short8*)&sWc[(nb * 16 + col) * LSTR + quad * 8];
                short8 b1 = *(const short8*)&sWc[(nb * 16 + col) * LSTR + 32 + quad * 8];
                p[nb] = __builtin_amdgcn_mfma_f32_16x16x32_bf16(a0, b0, p[nb], 0, 0, 0);
                p[nb] = __builtin_amdgcn_mfma_f32_16x16x32_bf16(a1, b1, p[nb], 0, 0, 0);
            }
#pragma unroll
            for (int reg = 0; reg < 4; reg++) {
                int sl = quad * 4 + reg;
                float tx = __shfl(dx, sl, 64), ty = __shfl(dy, sl, 64), tz = __shfl(dz, sl, 64);
#pragma unroll
                for (int nb = 0; nb < 4; nb++) {
                    float s0 = siluf(p[nb][reg] + cbv[nb]);
                    H2a[nb * 3 + 0] += s0 * tx;
                    H2a[nb * 3 + 1] += s0 * ty;
                    H2a[nb * 3 + 2] += s0 * tz;
                }
            }
        }

        // GEMM-V: v = he@fw1; wv = silu(comb*v + fb1) consumed in-register -> G
        {
            f32x4 v[4] = {{0.f,0.f,0.f,0.f},{0.f,0.f,0.f,0.f},{0.f,0.f,0.f,0.f},{0.f,0.f,0.f,0.f}};
#pragma unroll
            for (int nb = 0; nb < 4; nb++) {
                short8 b0 = *(const short8*)&sWf[(nb * 16 + col) * LSTR + quad * 8];
                short8 b1 = *(const short8*)&sWf[(nb * 16 + col) * LSTR + 32 + quad * 8];
                v[nb] = __builtin_amdgcn_mfma_f32_16x16x32_bf16(a0, b0, v[nb], 0, 0, 0);
                v[nb] = __builtin_amdgcn_mfma_f32_16x16x32_bf16(a1, b1, v[nb], 0, 0, 0);
            }
#pragma unroll
            for (int reg = 0; reg < 4; reg++) {
                int sl = quad * 4 + reg;
                float ti = __shfl(iv, sl, 64);
                float fx = __shfl(dx, sl, 64) * ti;
                float fy = __shfl(dy, sl, 64) * ti;
                float fz = __shfl(dz, sl, 64) * ti;
#pragma unroll
                for (int nb = 0; nb < 4; nb++) {
                    float w0 = siluf(cm[reg] * v[nb][reg] + fbv[nb]);
                    Ga[nb * 3 + 0] += w0 * fx;
                    Ga[nb * 3 + 1] += w0 * fy;
                    Ga[nb * 3 + 2] += w0 * fz;
                }
            }
        }
    }  // jt

    // ---- one-shot reductions (once per block) ----
#pragma unroll
    for (int nb = 0; nb < 4; nb++) {
        float v = redquad(hagA[nb]);
        if (quad == 0) atomicAdd(&sHag[nb * 16 + col], v);
    }
#pragma unroll
    for (int nb = 0; nb < 4; nb++) {
#pragma unroll
        for (int d = 0; d < 3; d++) {
            float v = redquad(H2a[nb * 3 + d]);
            if (quad == 0) atomicAdd(&sH2[(nb * 16 + col) * 3 + d], v);
            float g = redquad(Ga[nb * 3 + d]);
            if (quad == 0) atomicAdd(&sG[(nb * 16 + col) * 3 + d], g);
        }
    }
    sdx = wsum(sdx); sdy = wsum(sdy); sdz = wsum(sdz);
    if (lane == 0) {  // quads quadruplicate the rows -> exact 0.25 rescale
        atomicAdd(&sSd[0], 0.25f * sdx);
        atomicAdd(&sSd[1], 0.25f * sdy);
        atomicAdd(&sSd[2], 0.25f * sdz);
    }
    __syncthreads();  // all waves' LDS atomics done

    // ---- block-end finishes (were kE's serial shuffle chains) ----
    if (tid < 128) {
        int c = tid >> 2, d = tid & 3;
        if (d < 3) {
            float acc = fb2[c] * sSd[d];
#pragma unroll
            for (int m = 0; m < 64; m++) acc += fw2[m * 32 + c] * sG[m * 3 + d];
            combos[i * 96 + c * 3 + d] = acc;
        }
    } else if (tid < 131) {
        int d = tid - 128;
        float acc = 0.f;
#pragma unroll
        for (int n = 0; n < 64; n++) acc += cw2[n] * sH2[n * 3 + d];
        xupd[i * 3 + d] = acc;
    } else if (tid >= 192 && tid < 256) {
        hagg[i * 64 + tid - 192] = sHag[tid - 192];
    }
}

// ---- kE: post MLPs + node update + coordinate output (r0 form) ----
__global__ void kE(const float* __restrict__ h, const float* __restrict__ x,
                   const float* __restrict__ nw1, const float* __restrict__ nb1,
                   const float* __restrict__ nw2, const float* __restrict__ nb2,
                   const float* __restrict__ pw1, const float* __restrict__ pb1,
                   const float* __restrict__ pw2, const float* __restrict__ pb2,
                   const float* __restrict__ hagg, const float* __restrict__ combos,
                   const float* __restrict__ xupd, float* __restrict__ out) {
    const int i = blockIdx.x, o = threadIdx.x;
    const float invN = 1.0f / (float)NN;
    float r = 0.f;
    if (o < 32) {
        float v0 = combos[i * 96 + o * 3 + 0] * invN;
        float v1 = combos[i * 96 + o * 3 + 1] * invN;
        float v2 = combos[i * 96 + o * 3 + 2] * invN;
        r = v0 * v0 + v1 * v1 + v2 * v2;
    }
    float t1 = pb1[o];
#pragma unroll
    for (int k = 0; k < 32; k++) t1 += __shfl(r, k, 64) * pw1[k * 64 + o];
    t1 = siluf(t1);
    float hc = pb2[o];
#pragma unroll
    for (int k = 0; k < 64; k++) hc += __shfl(t1, k, 64) * pw2[k * 64 + o];
    float hi = h[i * 64 + o];
    float ha = hagg[i * 64 + o];
    float t2 = nb1[o];
#pragma unroll
    for (int k = 0; k < 64; k++) t2 += __shfl(hi, k, 64) * nw1[k * 64 + o];
#pragma unroll
    for (int k = 0; k < 64; k++) t2 += __shfl(ha, k, 64) * nw1[(64 + k) * 64 + o];
#pragma unroll
    for (int k = 0; k < 64; k++) t2 += __shfl(hc, k, 64) * nw1[(128 + k) * 64 + o];
    t2 = siluf(t2);
    float ho = hi + nb2[o];
#pragma unroll
    for (int k = 0; k < 64; k++) ho += __shfl(t2, k, 64) * nw2[k * 64 + o];
    out[i * 64 + o] = ho;
    if (o < 3)
        out[NN * 64 + i * 3 + o] = x[i * 3 + o] + xupd[i * 3 + o] * invN;
}

extern "C" void kernel_launch(void* const* d_in, const int* in_sizes, int n_in,
                              void* d_out, int out_size, void* d_ws, size_t ws_size,
                              hipStream_t stream) {
    (void)in_sizes; (void)n_in; (void)out_size; (void)ws_size;
    const float* h   = (const float*)d_in[0];
    const float* x   = (const float*)d_in[1];
    const float* ew1 = (const float*)d_in[2];
    const float* eb1 = (const float*)d_in[3];
    const float* ew2 = (const float*)d_in[4];
    const float* eb2 = (const float*)d_in[5];
    const float* nw1 = (const float*)d_in[6];
    const float* nb1 = (const float*)d_in[7];
    const float* nw2 = (const float*)d_in[8];
    const float* nb2 = (const float*)d_in[9];
    const float* cw1 = (const float*)d_in[10];
    const float* cb1 = (const float*)d_in[11];
    const float* cw2 = (const float*)d_in[12];
    const float* aw  = (const float*)d_in[13];
    const float* ab  = (const float*)d_in[14];
    const float* fw1 = (const float*)d_in[15];
    const float* fb1 = (const float*)d_in[16];
    const float* fw2 = (const float*)d_in[17];
    const float* fb2 = (const float*)d_in[18];
    const float* pw1 = (const float*)d_in[19];
    const float* pb1 = (const float*)d_in[20];
    const float* pw2 = (const float*)d_in[21];
    const float* pb2 = (const float*)d_in[22];
    const float* lg  = (const float*)d_in[23];
    float* out = (float*)d_out;

    float* W      = (float*)d_ws;
    float* ls     = W;                        // N*N
    float* HA     = ls + (size_t)NN * NN;     // N*64
    float* HB     = HA + NN * 64;             // N*64
    float* HBT    = HB + NN * 64;             // 64*N
    float* rowm   = HBT + NN * 64;            // N
    float* rowd   = rowm + NN;                // N
    float* hagg   = rowd + NN;                // N*64   (direct store)
    float* combos = hagg + NN * 64;           // N*96   (direct store)
    float* xupd   = combos + NN * 96;         // N*3    (direct store)
    float* wsv    = xupd + NN * 3;            // 64
    float* svb    = wsv + 64;                 // 1
    short* ew2T   = (short*)(svb + 4);        // 64*64 bf16
    short* cw1T   = ew2T + 64 * 64;
    short* fw1T   = cw1T + 64 * 64;
    short* fw2T   = fw1T + 64 * 64;           // 32*64 bf16 (legacy, unused)

    kA<<<NN + 65, 64, 0, stream>>>(h, ew1, eb1, ew2, cw1, fw1, fw2, aw, ab, eb2,
                                   HA, HB, HBT, ew2T, cw1T, fw1T, fw2T, wsv, svb);
    kBn<<<NN, 256, 0, stream>>>(x, ew1, HA, HBT, wsv, svb, lg, ls, rowm, rowd);
    kD<<<NN, 512, 0, stream>>>(x, ew1, eb2, cb1, fb1, lg, fw2, fb2, cw2,
                               HA, HB, ew2T, cw1T, fw1T, ls, rowm, rowd,
                               hagg, combos, xupd);
    kE<<<NN, 64, 0, stream>>>(h, x, nw1, nb1, nw2, nb2, pw1, pb1, pw2, pb2,
                              hagg, combos, xupd, out);
}